// Round 1
// 76.781 us; speedup vs baseline: 1.0566x; 1.0566x over previous
//
#include <hip/hip_runtime.h>

// NonLinearConv2d: ik[b,oc,h,w] = ALPHA * sum_{cin,kh,kw} [ sp2((v-t)/D) - sp2((v-t-VD)/D) ]
//   v = clip(x,0,9) zero-padded patch, t = clip(theta,1,8), sp2(a)=log1p(exp(a))^2
//
// Round 4 (this session):
//  * Chain is 3 graph nodes (was 4): prep -> build_lists -> nlmain.
//    - no hipMemsetAsync: prep writes 64 per-block partial maxima (all slots
//      written, so poisoned ws is harmless); build_lists reduces them in-wave.
//    - Ev = exp(clip(x)/D) computed ONCE in prep into ws (2 MB), instead of
//      4x-redundantly in every nlmain block's staging loop.
//  * nlmain staging is now a pure copy: 4x (aligned float4 load + ds_write_b128)
//    per thread + 1 constant halo store. Halo cells (input col -1/32, OOB rows)
//    are exp(0)=1.0f constants.
//  * LDS tile stride 34 -> 40 words so float4 interior writes are 16B-aligned.
//    Reads keep 2 lanes/bank (free per m136): lanes 32-63 offset by 40 mod 32 = 8.
//  * Tier structure unchanged from round 3 (verified absmax 1.9e-6):
//      t >= vmax+0.6   : dropped          (err <= ALPHA*288*e^-16 ~ 1.8e-8)
//      t >= vmax+0.131 : u<=0.175, series u^2*(C2 - C3 u + C4 u^2)
//      else            : exact, 2x __logf
//    u = Ev*Et with Et=exp(-t/D) in the per-oc list -> zero exp in hot loop.

#define B_    16
#define CIN_  32
#define H_    32
#define W_    32
#define OC_   64
#define CKK_  288

#define INV_D  13.333333333333334f
#define ALPHA_ 0.0005625f
#define KC     0.26359713811572677f   // e^{-4/3}
#define C2_    0.93051654475128f      // 1 - K^2
#define C3_    0.98168436111127f      // 1 - K^3
#define C4_    0.91224137800000f      // (11/12)(1 - K^4)

// LDS tile geometry (words): 32 cin x 4 rows x [pad,halo,32 interior,halo,pad]
#define TSTR   40                     // row stride; interior at word 4 (16B-aligned)
#define TSTRC  (4 * TSTR)             // 160: cin stride
#define TWORDS (CIN_ * TSTRC)         // 5120 floats = 20480 B

// ws layout (bytes)
#define WS_EV     0                               // float[16*32*32*32] = 2 MB
#define WS_PART   2097152                         // float[64]
#define WS_CNTA   2097664
#define WS_CNTB   2097920
#define WS_LISTA  2098176                         // int2[64][288]
#define WS_LISTB  (WS_LISTA + OC_*CKK_*8)
#define WS_NEEDED (WS_LISTB + OC_*CKK_*8)         // ~2.29 MB

__device__ __forceinline__ float clipf(float v, float lo, float hi) {
    return fminf(fmaxf(v, lo), hi);
}

// ---- node 1: Ev = exp(clip(x)/D) for all elements + per-block max partials ----
__global__ void prep(const float4* __restrict__ x4, float4* __restrict__ ev4,
                     float* __restrict__ part, int n4) {
    float m = 0.0f;
    for (int i = blockIdx.x * blockDim.x + threadIdx.x; i < n4;
         i += gridDim.x * blockDim.x) {
        float4 v = x4[i];
        float a = clipf(v.x, 0.0f, 9.0f);
        float b = clipf(v.y, 0.0f, 9.0f);
        float c = clipf(v.z, 0.0f, 9.0f);
        float d = clipf(v.w, 0.0f, 9.0f);
        m = fmaxf(m, fmaxf(fmaxf(a, b), fmaxf(c, d)));
        float4 e;
        e.x = __expf(a * INV_D);
        e.y = __expf(b * INV_D);
        e.z = __expf(c * INV_D);
        e.w = __expf(d * INV_D);
        ev4[i] = e;
    }
    #pragma unroll
    for (int off = 32; off > 0; off >>= 1)
        m = fmaxf(m, __shfl_down(m, off, 64));
    __shared__ float sm[4];
    const int lane = threadIdx.x & 63, wid = threadIdx.x >> 6;
    if (lane == 0) sm[wid] = m;
    __syncthreads();
    if (threadIdx.x == 0)
        part[blockIdx.x] = fmaxf(fmaxf(sm[0], sm[1]), fmaxf(sm[2], sm[3]));
}

// ---- node 2: per-oc tiered lists (reduces the 64 partials itself) ----
__global__ void build_lists(const float* __restrict__ theta,
                            const float* __restrict__ part,
                            int* __restrict__ cntA, int* __restrict__ cntB,
                            int2* __restrict__ listA, int2* __restrict__ listB) {
    __shared__ float svmax;
    __shared__ int sA, sB;
    if (threadIdx.x == 0) { sA = 0; sB = 0; }
    float m = (threadIdx.x < 64) ? part[threadIdx.x] : 0.0f;
    #pragma unroll
    for (int off = 32; off > 0; off >>= 1)
        m = fmaxf(m, __shfl_down(m, off, 64));
    if (threadIdx.x == 0) svmax = m;       // wave 0's lane 0 holds the reduce
    __syncthreads();

    const int oc = blockIdx.x;
    const float vmax = svmax;
    const float cutB = vmax + 0.6f;
    const float cutA = vmax + 0.131f;      // u <= 0.175 beyond this
    for (int j = threadIdx.x; j < CKK_; j += blockDim.x) {
        float t = clipf(theta[oc * CKK_ + j], 1.0f, 8.0f);
        if (t < cutB) {
            int cin = j / 9;
            int r   = j - cin * 9;
            int2 e;
            // LDS word offset inside Ev tile (thread adds rl*TSTR + w)
            e.x = cin * TSTRC + (r / 3) * TSTR + 3 + (r % 3);
            e.y = __float_as_int(__expf(-t * INV_D));   // Et
            if (t < cutA) { int i = atomicAdd(&sA, 1); listA[oc * CKK_ + i] = e; }
            else          { int i = atomicAdd(&sB, 1); listB[oc * CKK_ + i] = e; }
        }
    }
    __syncthreads();
    if (threadIdx.x == 0) { cntA[oc] = sA; cntB[oc] = sB; }
}

// ---- node 3: main compute ----
__launch_bounds__(256, 4)
__global__ void nlmain(const float* __restrict__ ev,
                       const int* __restrict__ cntA, const int* __restrict__ cntB,
                       const int2* __restrict__ listA, const int2* __restrict__ listB,
                       float* __restrict__ out) {
    __shared__ float sx[TWORDS];           // 20480 B -> 4 blocks/CU fits easily

    const int blk = blockIdx.x;            // b*64 + rp*4 + ocg
    const int ocg = blk & 3;
    const int rp  = (blk >> 2) & 15;
    const int b   = blk >> 6;

    // stage Ev tile: pure copy, no transcendentals.
    // thread -> (rowIdx = cin*4+rr, c4): 4 float4s each; rows OOB -> 1.0f.
    {
        const float4* evb = (const float4*)(ev) + b * (CIN_ * H_ * W_ / 4);
        const int c4 = threadIdx.x & 7;        // which float4 of the 32-col row
        const int r0 = threadIdx.x >> 3;       // 0..31
        #pragma unroll
        for (int s = 0; s < 4; ++s) {
            const int rowIdx = r0 + s * 32;    // 0..127 = cin*4 + rr
            const int cin = rowIdx >> 2;
            const int rr  = rowIdx & 3;
            const int ir  = rp * 2 - 1 + rr;
            float4 v = make_float4(1.0f, 1.0f, 1.0f, 1.0f);
            if ((unsigned)ir < (unsigned)H_)
                v = evb[(cin * H_ + ir) * (W_ / 4) + c4];
            *(float4*)&sx[rowIdx * TSTR + 4 + c4 * 4] = v;
        }
        // halo words (input col -1 / col 32) are exp(0)=1 always (pad or clip-0)
        const int hrow = threadIdx.x & 127;
        const int side = threadIdx.x >> 7;     // 0: word 3, 1: word 36
        sx[hrow * TSTR + 3 + side * 33] = 1.0f;
    }
    __syncthreads();

    const int lane = threadIdx.x & 63;
    const int wv   = threadIdx.x >> 6;
    const int rl   = lane >> 5;            // 0/1: which row of the pair
    const int w    = lane & 31;
    const int myoff = rl * TSTR + w;
    const int row  = rp * 2 + rl;

    const int ocbase = __builtin_amdgcn_readfirstlane(ocg * 16 + wv * 4);

    #pragma unroll
    for (int k = 0; k < 4; ++k) {
        const int oc = ocbase + k;
        const int ca = cntA[oc];
        const int cb = cntB[oc];
        const int2* __restrict__ LA = listA + oc * CKK_;
        const int2* __restrict__ LB = listB + oc * CKK_;

        float accA = 0.0f, accB = 0.0f;

        #pragma unroll 2
        for (int i = 0; i < ca; ++i) {
            const int2 e  = LA[i];                       // wave-uniform -> s_load
            const float u = sx[e.x + myoff] * __int_as_float(e.y);
            const float l1 = __logf(1.0f + u);
            const float l2 = __logf(fmaf(u, KC, 1.0f));
            accA += (l1 - l2) * (l1 + l2);
        }
        #pragma unroll 4
        for (int i = 0; i < cb; ++i) {
            const int2 e  = LB[i];                       // wave-uniform -> s_load
            const float u = sx[e.x + myoff] * __int_as_float(e.y);
            float p = fmaf(u, C4_, -C3_);
            p = fmaf(u, p, C2_);
            accB = fmaf(u * u, p, accB);
        }

        out[((b * OC_ + oc) * H_ + row) * W_ + w] = ALPHA_ * (accA + accB);
    }
}

// ---------- fallback (ws too small): known-correct monolithic kernel ----------
// No workspace, no vmax: conservative cutoff 9.6 (vmax <= 9) keeps every entry
// on the exact path. Slow but correct; never taken with the 256 MiB harness ws.
__launch_bounds__(256)
__global__ void nlconv_fallback(const float* __restrict__ x,
                                const float* __restrict__ theta,
                                float* __restrict__ out) {
    __shared__ int   s_base[CKK_];
    __shared__ float s_t[CKK_];
    __shared__ int   s_d[CKK_];
    __shared__ int   s_cnt;
    const int blk = blockIdx.x;
    const int b  = blk >> 6;
    const int oc = blk & 63;
    if (threadIdx.x == 0) s_cnt = 0;
    __syncthreads();
    const float cutoff = 9.6f;
    for (int j = threadIdx.x; j < CKK_; j += blockDim.x) {
        float t = clipf(theta[oc * CKK_ + j], 1.0f, 8.0f);
        if (t < cutoff) {
            int i = atomicAdd(&s_cnt, 1);
            int cin = j / 9;
            int r   = j - cin * 9;
            s_base[i] = cin * (H_ * W_);
            s_t[i]    = t;
            s_d[i]    = (r / 3) | ((r % 3) << 8);
        }
    }
    __syncthreads();
    const int cnt = s_cnt;
    const float* xb = x + b * (CIN_ * H_ * W_);
    const int w  = threadIdx.x & 31;
    const int h0 = threadIdx.x >> 5;
    float acc[4] = {0.f, 0.f, 0.f, 0.f};
    for (int i = 0; i < cnt; ++i) {
        const float t    = s_t[i];
        const int   base = s_base[i];
        const int   d    = s_d[i];
        const int   rdh  = (d & 0xff) - 1;
        const int   rdw  = (d >> 8) - 1;
        const int  col   = w + rdw;
        const bool colok = (unsigned)col < (unsigned)W_;
        const int  ccol  = min(max(col, 0), W_ - 1);
        const float tq   = t * INV_D;
        #pragma unroll
        for (int k = 0; k < 4; ++k) {
            const int  row   = h0 + k * 8 + rdh;
            const bool rowok = (unsigned)row < (unsigned)H_;
            const int  crow  = min(max(row, 0), H_ - 1);
            const float xv   = xb[base + crow * W_ + ccol];
            const float v    = (rowok && colok) ? clipf(xv, 0.0f, 9.0f) : 0.0f;
            const float arg  = fmaf(v, INV_D, -tq);
            const float e1   = __expf(arg);
            const float e2   = e1 * KC;
            const float l1   = __logf(1.0f + e1);
            const float l2   = __logf(1.0f + e2);
            acc[k] += (l1 - l2) * (l1 + l2);
        }
    }
    float* ob = out + (b * OC_ + oc) * (H_ * W_);
    #pragma unroll
    for (int k = 0; k < 4; ++k)
        ob[(h0 + k * 8) * W_ + w] = ALPHA_ * acc[k];
}

extern "C" void kernel_launch(void* const* d_in, const int* in_sizes, int n_in,
                              void* d_out, int out_size, void* d_ws, size_t ws_size,
                              hipStream_t stream) {
    const float* x     = (const float*)d_in[0];
    const float* theta = (const float*)d_in[1];
    float* out = (float*)d_out;
    char* ws = (char*)d_ws;

    if (ws_size >= (size_t)WS_NEEDED) {
        float* evbuf = (float*)(ws + WS_EV);
        float* part  = (float*)(ws + WS_PART);
        int*  cntA   = (int*)(ws + WS_CNTA);
        int*  cntB   = (int*)(ws + WS_CNTB);
        int2* listA  = (int2*)(ws + WS_LISTA);
        int2* listB  = (int2*)(ws + WS_LISTB);

        const int n4 = (B_ * CIN_ * H_ * W_) / 4;
        // all 64 part[] slots written unconditionally -> no memset needed
        prep<<<64, 256, 0, stream>>>((const float4*)x, (float4*)evbuf, part, n4);
        build_lists<<<OC_, 128, 0, stream>>>(theta, part, cntA, cntB, listA, listB);
        nlmain<<<B_ * 16 * 4, 256, 0, stream>>>(evbuf, cntA, cntB, listA, listB, out);
    } else {
        nlconv_fallback<<<B_ * OC_, 256, 0, stream>>>(x, theta, out);
    }
}

// Round 2
// 73.604 us; speedup vs baseline: 1.1022x; 1.0432x over previous
//
#include <hip/hip_runtime.h>

// NonLinearConv2d: ik[b,oc,h,w] = ALPHA * sum_{cin,kh,kw} [ sp2((v-t)/D) - sp2((v-t-VD)/D) ]
//   v = clip(x,0,9) zero-padded patch, t = clip(theta,1,8), sp2(a)=log1p(exp(a))^2
//
// Round 5 (this session): 2 graph nodes (was 3).
//  * The vmax -> build_lists dependency is removed by bucket-sorting each oc's
//    288 entries by t (128 buckets over [1,8], width 7/128) with a per-oc
//    prefix table boff[129]. List build no longer needs vmax, so it runs as
//    blocks 128..191 of the SAME dispatch whose blocks 0..127 compute
//    Ev = exp(clip(x)/D) and per-block max partials.
//  * nlmain reduces the 128 partials itself (wave 0, L2-hot) and converts vmax
//    into bucket cuts:  kA = ceil((vmax-0.868)*128/7)  (exact tier below),
//                       kB = ceil((vmax-0.399)*128/7)  (dropped at/above).
//    Bucket-conservative in the SAFE direction: boundary entries promoted to
//    the more-exact tier; drops still guarantee t >= vmax+0.6 (err <= 1.8e-8).
//    Series tier still guarantees t >= vmax+0.131 -> u <= 0.175.
//  * Hot loops / LDS tile / staging identical to the verified round-4 kernel
//    (absmax 1.9e-6): u = Ev*Et, zero transcendentals in the hot loop,
//      exact tier: 2x __logf;  series tier: u^2*(C2 - C3 u + C4 u^2).

#define B_    16
#define CIN_  32
#define H_    32
#define W_    32
#define OC_   64
#define CKK_  288

#define INV_D  13.333333333333334f
#define ALPHA_ 0.0005625f
#define KC     0.26359713811572677f   // e^{-4/3}
#define C2_    0.93051654475128f      // 1 - K^2
#define C3_    0.98168436111127f      // 1 - K^3
#define C4_    0.91224137800000f      // (11/12)(1 - K^4)

// t-bucketing
#define NB      128
#define BSCALE  18.285714285714285f   // NB / 7
#define EVB_    128                   // Ev-computing blocks in node 1

// LDS tile geometry (words): 32 cin x 4 rows x [pad,halo,32 interior,halo,pad]
#define TSTR   40                     // row stride; interior at word 4 (16B-aligned)
#define TSTRC  (4 * TSTR)             // 160: cin stride
#define TWORDS (CIN_ * TSTRC)         // 5120 floats = 20480 B

// ws layout (bytes)
#define WS_EV     0                               // float[16*32*32*32] = 2 MB
#define WS_PART   2097152                         // float[128]
#define WS_BOFF   2097664                         // int[64][129] = 33024
#define WS_ELIST  2130688                         // int2[64][288] = 147456
#define WS_NEEDED 2278144

__device__ __forceinline__ float clipf(float v, float lo, float hi) {
    return fminf(fmaxf(v, lo), hi);
}

// ---- node 1: blocks [0,128): Ev + max partials; blocks [128,192): lists ----
__global__ void prep_build(const float4* __restrict__ x4, float4* __restrict__ ev4,
                           float* __restrict__ part,
                           const float* __restrict__ theta,
                           int* __restrict__ boff, int2* __restrict__ elist,
                           int n4) {
    if (blockIdx.x < EVB_) {
        // ---------------- Ev = exp(clip(x)/D) + per-block max ----------------
        float m = 0.0f;
        for (int i = blockIdx.x * blockDim.x + threadIdx.x; i < n4;
             i += EVB_ * 256) {
            float4 v = x4[i];
            float a = clipf(v.x, 0.0f, 9.0f);
            float b = clipf(v.y, 0.0f, 9.0f);
            float c = clipf(v.z, 0.0f, 9.0f);
            float d = clipf(v.w, 0.0f, 9.0f);
            m = fmaxf(m, fmaxf(fmaxf(a, b), fmaxf(c, d)));
            float4 e;
            e.x = __expf(a * INV_D);
            e.y = __expf(b * INV_D);
            e.z = __expf(c * INV_D);
            e.w = __expf(d * INV_D);
            ev4[i] = e;
        }
        #pragma unroll
        for (int off = 32; off > 0; off >>= 1)
            m = fmaxf(m, __shfl_down(m, off, 64));
        __shared__ float sm[4];
        const int lane = threadIdx.x & 63, wid = threadIdx.x >> 6;
        if (lane == 0) sm[wid] = m;
        __syncthreads();
        if (threadIdx.x == 0)
            part[blockIdx.x] = fmaxf(fmaxf(sm[0], sm[1]), fmaxf(sm[2], sm[3]));
    } else {
        // ------------- bucket-sorted list for oc = blockIdx.x-EVB_ -----------
        const int oc = blockIdx.x - EVB_;
        __shared__ int   hist[NB];        // histogram, then running counters
        __shared__ int   boffsh[NB + 1];
        __shared__ int   keys[CKK_];
        __shared__ int   exs[CKK_];
        __shared__ float ets[CKK_];
        for (int k = threadIdx.x; k < NB; k += 256) hist[k] = 0;
        __syncthreads();
        for (int j = threadIdx.x; j < CKK_; j += 256) {
            float t = clipf(theta[oc * CKK_ + j], 1.0f, 8.0f);
            int key = (int)((t - 1.0f) * BSCALE);
            key = key > (NB - 1) ? (NB - 1) : (key < 0 ? 0 : key);
            keys[j] = key;
            int cin = j / 9;
            int r   = j - cin * 9;
            exs[j]  = cin * TSTRC + (r / 3) * TSTR + 3 + (r % 3);
            ets[j]  = __expf(-t * INV_D);
            atomicAdd(&hist[key], 1);
        }
        __syncthreads();
        if (threadIdx.x == 0) {           // serial scan; resets hist for scatter
            int run = 0;
            for (int k = 0; k < NB; ++k) {
                boffsh[k] = run;
                run += hist[k];
                hist[k] = 0;
            }
            boffsh[NB] = run;             // == 288
        }
        __syncthreads();
        for (int j = threadIdx.x; j < CKK_; j += 256) {
            const int key = keys[j];
            const int d   = boffsh[key] + atomicAdd(&hist[key], 1);
            elist[oc * CKK_ + d] = make_int2(exs[j], __float_as_int(ets[j]));
        }
        for (int k = threadIdx.x; k <= NB; k += 256)
            boff[oc * (NB + 1) + k] = boffsh[k];
    }
}

// ---- node 2: main compute ----
__launch_bounds__(256, 4)
__global__ void nlmain(const float* __restrict__ ev,
                       const float* __restrict__ part,
                       const int* __restrict__ boff,
                       const int2* __restrict__ elist,
                       float* __restrict__ out) {
    __shared__ float sx[TWORDS];           // 20480 B
    __shared__ float svmax;

    const int blk = blockIdx.x;            // b*64 + rp*4 + ocg
    const int ocg = blk & 3;
    const int rp  = (blk >> 2) & 15;
    const int b   = blk >> 6;

    // stage Ev tile: pure copy, no transcendentals.
    {
        const float4* evb = (const float4*)(ev) + b * (CIN_ * H_ * W_ / 4);
        const int c4 = threadIdx.x & 7;        // which float4 of the 32-col row
        const int r0 = threadIdx.x >> 3;       // 0..31
        #pragma unroll
        for (int s = 0; s < 4; ++s) {
            const int rowIdx = r0 + s * 32;    // 0..127 = cin*4 + rr
            const int cin = rowIdx >> 2;
            const int rr  = rowIdx & 3;
            const int ir  = rp * 2 - 1 + rr;
            float4 v = make_float4(1.0f, 1.0f, 1.0f, 1.0f);
            if ((unsigned)ir < (unsigned)H_)
                v = evb[(cin * H_ + ir) * (W_ / 4) + c4];
            *(float4*)&sx[rowIdx * TSTR + 4 + c4 * 4] = v;
        }
        // halo words (input col -1 / col 32) are exp(0)=1 always (pad or clip-0)
        const int hrow = threadIdx.x & 127;
        const int side = threadIdx.x >> 7;     // 0: word 3, 1: word 36
        sx[hrow * TSTR + 3 + side * 33] = 1.0f;
    }
    // wave 0 reduces the 128 vmax partials (overlaps other waves' staging)
    if (threadIdx.x < 64) {
        float m = fmaxf(part[threadIdx.x], part[threadIdx.x + 64]);
        #pragma unroll
        for (int off = 32; off > 0; off >>= 1)
            m = fmaxf(m, __shfl_down(m, off, 64));
        if (threadIdx.x == 0) svmax = m;
    }
    __syncthreads();

    // bucket cuts (wave-uniform): series-safe and drop-safe by construction
    const float vmax = svmax;
    int kA = (int)ceilf((vmax - 0.868f) * BSCALE);   // exact tier: buckets < kA
    int kB = (int)ceilf((vmax - 0.399f) * BSCALE);   // dropped:    buckets >= kB
    kA = kA < 0 ? 0 : (kA > NB ? NB : kA);
    kB = kB < 0 ? 0 : (kB > NB ? NB : kB);
    kA = __builtin_amdgcn_readfirstlane(kA);
    kB = __builtin_amdgcn_readfirstlane(kB);

    const int lane = threadIdx.x & 63;
    const int wv   = threadIdx.x >> 6;
    const int rl   = lane >> 5;            // 0/1: which row of the pair
    const int w    = lane & 31;
    const int myoff = rl * TSTR + w;
    const int row  = rp * 2 + rl;

    const int ocbase = __builtin_amdgcn_readfirstlane(ocg * 16 + wv * 4);

    #pragma unroll
    for (int k = 0; k < 4; ++k) {
        const int oc = ocbase + k;
        const int* bo = boff + oc * (NB + 1);
        const int ca = __builtin_amdgcn_readfirstlane(bo[kA]);
        const int cb = __builtin_amdgcn_readfirstlane(bo[kB]);
        const int2* __restrict__ L = elist + oc * CKK_;

        float accA = 0.0f, accB = 0.0f;

        #pragma unroll 2
        for (int i = 0; i < ca; ++i) {                   // exact tier
            const int2 e  = L[i];                        // wave-uniform -> s_load
            const float u = sx[e.x + myoff] * __int_as_float(e.y);
            const float l1 = __logf(1.0f + u);
            const float l2 = __logf(fmaf(u, KC, 1.0f));
            accA += (l1 - l2) * (l1 + l2);
        }
        #pragma unroll 4
        for (int i = ca; i < cb; ++i) {                  // series tier, u<=0.175
            const int2 e  = L[i];                        // wave-uniform -> s_load
            const float u = sx[e.x + myoff] * __int_as_float(e.y);
            float p = fmaf(u, C4_, -C3_);
            p = fmaf(u, p, C2_);
            accB = fmaf(u * u, p, accB);
        }

        out[((b * OC_ + oc) * H_ + row) * W_ + w] = ALPHA_ * (accA + accB);
    }
}

// ---------- fallback (ws too small): known-correct monolithic kernel ----------
// No workspace, no vmax: conservative cutoff 9.6 (vmax <= 9) keeps every entry
// on the exact path. Slow but correct; never taken with the harness ws.
__launch_bounds__(256)
__global__ void nlconv_fallback(const float* __restrict__ x,
                                const float* __restrict__ theta,
                                float* __restrict__ out) {
    __shared__ int   s_base[CKK_];
    __shared__ float s_t[CKK_];
    __shared__ int   s_d[CKK_];
    __shared__ int   s_cnt;
    const int blk = blockIdx.x;
    const int b  = blk >> 6;
    const int oc = blk & 63;
    if (threadIdx.x == 0) s_cnt = 0;
    __syncthreads();
    const float cutoff = 9.6f;
    for (int j = threadIdx.x; j < CKK_; j += blockDim.x) {
        float t = clipf(theta[oc * CKK_ + j], 1.0f, 8.0f);
        if (t < cutoff) {
            int i = atomicAdd(&s_cnt, 1);
            int cin = j / 9;
            int r   = j - cin * 9;
            s_base[i] = cin * (H_ * W_);
            s_t[i]    = t;
            s_d[i]    = (r / 3) | ((r % 3) << 8);
        }
    }
    __syncthreads();
    const int cnt = s_cnt;
    const float* xb = x + b * (CIN_ * H_ * W_);
    const int w  = threadIdx.x & 31;
    const int h0 = threadIdx.x >> 5;
    float acc[4] = {0.f, 0.f, 0.f, 0.f};
    for (int i = 0; i < cnt; ++i) {
        const float t    = s_t[i];
        const int   base = s_base[i];
        const int   d    = s_d[i];
        const int   rdh  = (d & 0xff) - 1;
        const int   rdw  = (d >> 8) - 1;
        const int  col   = w + rdw;
        const bool colok = (unsigned)col < (unsigned)W_;
        const int  ccol  = min(max(col, 0), W_ - 1);
        const float tq   = t * INV_D;
        #pragma unroll
        for (int k = 0; k < 4; ++k) {
            const int  row   = h0 + k * 8 + rdh;
            const bool rowok = (unsigned)row < (unsigned)H_;
            const int  crow  = min(max(row, 0), H_ - 1);
            const float xv   = xb[base + crow * W_ + ccol];
            const float v    = (rowok && colok) ? clipf(xv, 0.0f, 9.0f) : 0.0f;
            const float arg  = fmaf(v, INV_D, -tq);
            const float e1   = __expf(arg);
            const float e2   = e1 * KC;
            const float l1   = __logf(1.0f + e1);
            const float l2   = __logf(1.0f + e2);
            acc[k] += (l1 - l2) * (l1 + l2);
        }
    }
    float* ob = out + (b * OC_ + oc) * (H_ * W_);
    #pragma unroll
    for (int k = 0; k < 4; ++k)
        ob[(h0 + k * 8) * W_ + w] = ALPHA_ * acc[k];
}

extern "C" void kernel_launch(void* const* d_in, const int* in_sizes, int n_in,
                              void* d_out, int out_size, void* d_ws, size_t ws_size,
                              hipStream_t stream) {
    const float* x     = (const float*)d_in[0];
    const float* theta = (const float*)d_in[1];
    float* out = (float*)d_out;
    char* ws = (char*)d_ws;

    if (ws_size >= (size_t)WS_NEEDED) {
        float* evbuf = (float*)(ws + WS_EV);
        float* part  = (float*)(ws + WS_PART);
        int*   boff  = (int*)(ws + WS_BOFF);
        int2*  elist = (int2*)(ws + WS_ELIST);

        const int n4 = (B_ * CIN_ * H_ * W_) / 4;
        // all 128 part[] slots and all 64*(NB+1) boff slots and all 64*288
        // elist slots are written unconditionally -> poisoned ws is harmless
        prep_build<<<EVB_ + OC_, 256, 0, stream>>>(
            (const float4*)x, (float4*)evbuf, part, theta, boff, elist, n4);
        nlmain<<<B_ * 16 * 4, 256, 0, stream>>>(evbuf, part, boff, elist, out);
    } else {
        nlconv_fallback<<<B_ * OC_, 256, 0, stream>>>(x, theta, out);
    }
}